// Round 15
// baseline (255.355 us; speedup 1.0000x reference)
//
#include <hip/hip_runtime.h>
#include <hip/hip_bf16.h>

typedef unsigned short u16;
typedef unsigned int u32;
typedef __bf16 bf16x8 __attribute__((ext_vector_type(8)));
typedef float f32x4 __attribute__((ext_vector_type(4)));

#define NN 50000
#define NE 640000
#define DH 128
#define NTILES (NN / 16)        // 3125, exact
#define NBLK ((NN + 255) / 256) // 196 scan blocks

__device__ __forceinline__ u16 f2bf(float f) {
  u32 i = __float_as_uint(f);
  u32 r = (i + 0x7FFFu + ((i >> 16) & 1u)) >> 16;   // RNE
  return (u16)r;
}
__device__ __forceinline__ float bflo(u32 v) { return __uint_as_float(v << 16); }
__device__ __forceinline__ float bfhi(u32 v) { return __uint_as_float(v & 0xFFFF0000u); }

__device__ __forceinline__ bf16x8 pack8(f32x4 lo, f32x4 hi) {
  union { u16 u[8]; bf16x8 v; } r;
  r.u[0] = f2bf(lo[0]); r.u[1] = f2bf(lo[1]); r.u[2] = f2bf(lo[2]); r.u[3] = f2bf(lo[3]);
  r.u[4] = f2bf(hi[0]); r.u[5] = f2bf(hi[1]); r.u[6] = f2bf(hi[2]); r.u[7] = f2bf(hi[3]);
  return r.v;
}

// ------- cast weights fp32->bf16, copy x -> out[:,0:128], zero cnt -----------
// wb layout (elements): pre_w@0, wl0@16384, wr0@32768, wl1@49152, wr1@65536, lin_w@81920
__global__ void cast_all(const float* __restrict__ x,
                         const float* __restrict__ pw, const float* __restrict__ wl0,
                         const float* __restrict__ wr0, const float* __restrict__ wl1,
                         const float* __restrict__ wr1, const float* __restrict__ lw,
                         float* __restrict__ out, u16* __restrict__ wb,
                         int* __restrict__ cnt) {
  int idx = blockIdx.x * blockDim.x + threadIdx.x;
  long i4 = (long)idx * 4;
  const long XCNT = (long)NN * DH;      // 6,400,000
  const long WCNT = 114688;
  if (i4 < XCNT) {
    float4 v = *(const float4*)(x + i4);
    long row = i4 >> 7;
    long col = i4 & 127;
    *(float4*)(out + row * 384 + col) = v;
  } else if (i4 < XCNT + WCNT) {
    long w = i4 - XCNT;
    const float* src; long off;
    if (w < 16384)      { src = pw;  off = 0; }
    else if (w < 32768) { src = wl0; off = 16384; }
    else if (w < 49152) { src = wr0; off = 32768; }
    else if (w < 65536) { src = wl1; off = 49152; }
    else if (w < 81920) { src = wr1; off = 65536; }
    else                { src = lw;  off = 81920; }
    float4 v = *(const float4*)(src + (w - off));
    u32 a = (u32)f2bf(v.x) | ((u32)f2bf(v.y) << 16);
    u32 b = (u32)f2bf(v.z) | ((u32)f2bf(v.w) << 16);
    *(uint2*)(wb + w) = make_uint2(a, b);
  } else if (i4 < XCNT + WCNT + NN) {
    long c = i4 - XCNT - WCNT;           // NN divisible by 4
    *(int4*)(cnt + c) = make_int4(0, 0, 0, 0);
  }
}

// ---------------- CSR build ----------------
__global__ void count_kernel(const int* __restrict__ ei, int* __restrict__ cnt) {
  int e = blockIdx.x * blockDim.x + threadIdx.x;
  if (e < NE) atomicAdd(&cnt[ei[NE + e]], 1);
}

__global__ __launch_bounds__(256) void scan_part(const int* __restrict__ cnt,
                                                 int* __restrict__ partial) {
  __shared__ int sm[4];
  int i = blockIdx.x * 256 + threadIdx.x;
  int s = (i < NN) ? cnt[i] : 0;
  s += __shfl_xor(s, 1);  s += __shfl_xor(s, 2);  s += __shfl_xor(s, 4);
  s += __shfl_xor(s, 8);  s += __shfl_xor(s, 16); s += __shfl_xor(s, 32);
  if ((threadIdx.x & 63) == 0) sm[threadIdx.x >> 6] = s;
  __syncthreads();
  if (threadIdx.x == 0) partial[blockIdx.x] = sm[0] + sm[1] + sm[2] + sm[3];
}

__global__ __launch_bounds__(256) void scan_top(int* __restrict__ partial) {
  __shared__ int sm[256];
  int tid = threadIdx.x;
  int v = (tid < NBLK) ? partial[tid] : 0;
  sm[tid] = v;
  __syncthreads();
  for (int d = 1; d < 256; d <<= 1) {
    int t = (tid >= d) ? sm[tid - d] : 0;
    __syncthreads();
    sm[tid] += t;
    __syncthreads();
  }
  if (tid < NBLK) partial[tid] = sm[tid] - v;   // exclusive prefix
}

__global__ __launch_bounds__(256) void scan_final(const int* __restrict__ cnt,
                                                  const int* __restrict__ partial,
                                                  int* __restrict__ off,
                                                  int* __restrict__ fillpos) {
  __shared__ int sm[256];
  int tid = threadIdx.x;
  int i = blockIdx.x * 256 + tid;
  int v = (i < NN) ? cnt[i] : 0;
  sm[tid] = v;
  __syncthreads();
  for (int d = 1; d < 256; d <<= 1) {
    int t = (tid >= d) ? sm[tid - d] : 0;
    __syncthreads();
    sm[tid] += t;
    __syncthreads();
  }
  int excl = sm[tid] - v + partial[blockIdx.x];
  if (i < NN) { off[i] = excl; fillpos[i] = excl; }
  if (i == 0) off[NN] = NE;
}

__global__ void fill_kernel(const int* __restrict__ ei, int* __restrict__ fillpos,
                            int* __restrict__ srcs) {
  int e = blockIdx.x * blockDim.x + threadIdx.x;
  if (e < NE) {
    int d = ei[NE + e];
    int p = atomicAdd(&fillpos[d], 1);
    srcs[p] = ei[e];
  }
}

// ---------------- pre-MP: fp32-A GEMM + bias + LN + ReLU ------------------
__global__ __launch_bounds__(256) void pre_gemm(const float* __restrict__ X,
                                                const u16* __restrict__ W,
                                                const float* __restrict__ bias,
                                                const float* __restrict__ g,
                                                const float* __restrict__ be,
                                                u16* __restrict__ outh) {
  __shared__ u16 st[16 * 136];
  __shared__ float redS[4][16], redQ[4][16];
  int lane = threadIdx.x & 63;
  int wid = threadIdx.x >> 6;
  int ntile = blockIdx.x;
  int rA = lane & 15;
  int ksel = lane >> 4;

  f32x4 acc[2];
  acc[0] = (f32x4){0.f,0.f,0.f,0.f};
  acc[1] = (f32x4){0.f,0.f,0.f,0.f};

  const float* xrow = X + (size_t)(ntile * 16 + rA) * DH + ksel * 8;
  #pragma unroll
  for (int ks = 0; ks < 4; ++ks) {
    f32x4 lo = *(const f32x4*)(xrow + ks * 32);
    f32x4 hi = *(const f32x4*)(xrow + ks * 32 + 4);
    bf16x8 af = pack8(lo, hi);
    #pragma unroll
    for (int jt = 0; jt < 2; ++jt) {
      const u16* wf = W + (size_t)(wid * 32 + jt * 16 + rA) * DH + ksel * 8 + ks * 32;
      acc[jt] = __builtin_amdgcn_mfma_f32_16x16x32_bf16(af, *(const bf16x8*)wf, acc[jt], 0, 0, 0);
    }
  }

  int jcol = lane & 15;
  int rbase = (lane >> 4) * 4;
  float gv[2], bev[2];
  #pragma unroll
  for (int jt = 0; jt < 2; ++jt) {
    int j = wid * 32 + jt * 16 + jcol;
    float bi = bias[j];
    gv[jt] = g[j]; bev[jt] = be[j];
    #pragma unroll
    for (int r = 0; r < 4; ++r) acc[jt][r] += bi;
  }
  #pragma unroll
  for (int r = 0; r < 4; ++r) {
    float s = acc[0][r] + acc[1][r];
    float q = acc[0][r]*acc[0][r] + acc[1][r]*acc[1][r];
    s += __shfl_xor(s, 1); s += __shfl_xor(s, 2);
    s += __shfl_xor(s, 4); s += __shfl_xor(s, 8);
    q += __shfl_xor(q, 1); q += __shfl_xor(q, 2);
    q += __shfl_xor(q, 4); q += __shfl_xor(q, 8);
    if (jcol == 0) { redS[wid][rbase + r] = s; redQ[wid][rbase + r] = q; }
  }
  __syncthreads();
  #pragma unroll
  for (int r = 0; r < 4; ++r) {
    int row = rbase + r;
    float S = redS[0][row] + redS[1][row] + redS[2][row] + redS[3][row];
    float Q = redQ[0][row] + redQ[1][row] + redQ[2][row] + redQ[3][row];
    float mean = S * (1.0f / 128.0f);
    float var = Q * (1.0f / 128.0f) - mean * mean;
    float rs = rsqrtf(var + 1e-5f);
    #pragma unroll
    for (int jt = 0; jt < 2; ++jt) {
      float y = (acc[jt][r] - mean) * rs * gv[jt] + bev[jt];
      y = fmaxf(y, 0.f);
      st[row * 136 + wid * 32 + jt * 16 + jcol] = f2bf(y);
    }
  }
  __syncthreads();
  int t = threadIdx.x;
  int row = t >> 4;
  int c = t & 15;
  uint4 v = *(const uint4*)&st[row * 136 + c * 8];
  *(uint4*)(outh + (size_t)(ntile * 16 + row) * DH + c * 8) = v;
}

// ------- SAGE layer fused: gather-mean + dual GEMM + bias + LN + ReLU --------
// 16-lane sub per node; 8-deep batched edge loads (32 rows in flight/wave),
// idx loads batched ahead of row loads. Then column-quadrant dual MFMA.
#define ACC8(v) { a0 += bflo(v.x); a1 += bfhi(v.x); a2 += bflo(v.y); a3 += bfhi(v.y); \
                  a4 += bflo(v.z); a5 += bfhi(v.z); a6 += bflo(v.w); a7 += bfhi(v.w); }
__global__ __launch_bounds__(256) void sage_fused(const u16* __restrict__ h,
                                                  const int* __restrict__ off,
                                                  const int* __restrict__ srcs,
                                                  const u16* __restrict__ WL,
                                                  const u16* __restrict__ WR,
                                                  const float* __restrict__ bias,
                                                  const float* __restrict__ g,
                                                  const float* __restrict__ be,
                                                  u16* __restrict__ outh) {
  __shared__ u16 aggt[16 * 136];
  __shared__ u16 st[16 * 136];
  __shared__ float redS[4][16], redQ[4][16];
  int lane = threadIdx.x & 63;
  int wid = threadIdx.x >> 6;
  int ntile = blockIdx.x;
  int sub = lane >> 4;        // 0..3: which node of the wave's quad
  int c16 = lane & 15;        // 16B chunk of the row
  int rA = c16;
  int ksel = sub;

  // preload root A fragments (this block's own 16 h-rows) before gathering
  const u16* arow = h + (size_t)(ntile * 16 + rA) * DH + ksel * 8;
  bf16x8 afr[4];
  #pragma unroll
  for (int ks = 0; ks < 4; ++ks) afr[ks] = *(const bf16x8*)(arow + ks * 32);

  // gather-mean: sub s of wave w owns node (w*4+s); 8-deep load batching
  {
    int lrow = wid * 4 + sub;
    int node = ntile * 16 + lrow;
    int e0 = off[node], e1 = off[node + 1];
    float a0=0,a1=0,a2=0,a3=0,a4=0,a5=0,a6=0,a7=0;
    const u16* hc = h + c16 * 8;
    int e = e0;
    for (; e + 7 < e1; e += 8) {
      int i0 = srcs[e],   i1 = srcs[e+1], i2 = srcs[e+2], i3 = srcs[e+3];
      int i4_ = srcs[e+4], i5 = srcs[e+5], i6 = srcs[e+6], i7 = srcs[e+7];
      uint4 v0 = *(const uint4*)(hc + (size_t)i0 * DH);
      uint4 v1 = *(const uint4*)(hc + (size_t)i1 * DH);
      uint4 v2 = *(const uint4*)(hc + (size_t)i2 * DH);
      uint4 v3 = *(const uint4*)(hc + (size_t)i3 * DH);
      uint4 v4 = *(const uint4*)(hc + (size_t)i4_ * DH);
      uint4 v5 = *(const uint4*)(hc + (size_t)i5 * DH);
      uint4 v6 = *(const uint4*)(hc + (size_t)i6 * DH);
      uint4 v7 = *(const uint4*)(hc + (size_t)i7 * DH);
      ACC8(v0); ACC8(v1); ACC8(v2); ACC8(v3);
      ACC8(v4); ACC8(v5); ACC8(v6); ACC8(v7);
    }
    if (e + 3 < e1) {
      int i0 = srcs[e], i1 = srcs[e+1], i2 = srcs[e+2], i3 = srcs[e+3];
      uint4 v0 = *(const uint4*)(hc + (size_t)i0 * DH);
      uint4 v1 = *(const uint4*)(hc + (size_t)i1 * DH);
      uint4 v2 = *(const uint4*)(hc + (size_t)i2 * DH);
      uint4 v3 = *(const uint4*)(hc + (size_t)i3 * DH);
      ACC8(v0); ACC8(v1); ACC8(v2); ACC8(v3);
      e += 4;
    }
    for (; e < e1; ++e) {
      int s = srcs[e];
      uint4 v = *(const uint4*)(hc + (size_t)s * DH);
      ACC8(v);
    }
    int deg = e1 - e0;
    float inv = 1.0f / (float)(deg > 0 ? deg : 1);
    uint4 o;
    o.x = (u32)f2bf(a0 * inv) | ((u32)f2bf(a1 * inv) << 16);
    o.y = (u32)f2bf(a2 * inv) | ((u32)f2bf(a3 * inv) << 16);
    o.z = (u32)f2bf(a4 * inv) | ((u32)f2bf(a5 * inv) << 16);
    o.w = (u32)f2bf(a6 * inv) | ((u32)f2bf(a7 * inv) << 16);
    *(uint4*)&aggt[lrow * 136 + c16 * 8] = o;
  }
  __syncthreads();

  // dual MFMA: agg@WL + root@WR, wave owns cols [wid*32, wid*32+32)
  f32x4 acc[2];
  acc[0] = (f32x4){0.f,0.f,0.f,0.f};
  acc[1] = (f32x4){0.f,0.f,0.f,0.f};
  #pragma unroll
  for (int ks = 0; ks < 4; ++ks) {
    bf16x8 afa = *(const bf16x8*)&aggt[rA * 136 + ksel * 8 + ks * 32];
    #pragma unroll
    for (int jt = 0; jt < 2; ++jt) {
      const u16* wf = WL + (size_t)(wid * 32 + jt * 16 + rA) * DH + ksel * 8 + ks * 32;
      acc[jt] = __builtin_amdgcn_mfma_f32_16x16x32_bf16(afa, *(const bf16x8*)wf, acc[jt], 0, 0, 0);
    }
  }
  #pragma unroll
  for (int ks = 0; ks < 4; ++ks) {
    #pragma unroll
    for (int jt = 0; jt < 2; ++jt) {
      const u16* wf = WR + (size_t)(wid * 32 + jt * 16 + rA) * DH + ksel * 8 + ks * 32;
      acc[jt] = __builtin_amdgcn_mfma_f32_16x16x32_bf16(afr[ks], *(const bf16x8*)wf, acc[jt], 0, 0, 0);
    }
  }

  // epilogue: D[row=(lane>>4)*4+r][col local=lane&15]; global col = wid*32+jt*16+jcol
  int jcol = lane & 15;
  int rbase = (lane >> 4) * 4;
  float gv[2], bev[2];
  #pragma unroll
  for (int jt = 0; jt < 2; ++jt) {
    int j = wid * 32 + jt * 16 + jcol;
    float bi = bias[j];
    gv[jt] = g[j]; bev[jt] = be[j];
    #pragma unroll
    for (int r = 0; r < 4; ++r) acc[jt][r] += bi;
  }
  #pragma unroll
  for (int r = 0; r < 4; ++r) {
    float s = acc[0][r] + acc[1][r];
    float q = acc[0][r]*acc[0][r] + acc[1][r]*acc[1][r];
    s += __shfl_xor(s, 1); s += __shfl_xor(s, 2);
    s += __shfl_xor(s, 4); s += __shfl_xor(s, 8);
    q += __shfl_xor(q, 1); q += __shfl_xor(q, 2);
    q += __shfl_xor(q, 4); q += __shfl_xor(q, 8);
    if (jcol == 0) { redS[wid][rbase + r] = s; redQ[wid][rbase + r] = q; }
  }
  __syncthreads();
  #pragma unroll
  for (int r = 0; r < 4; ++r) {
    int row = rbase + r;
    float S = redS[0][row] + redS[1][row] + redS[2][row] + redS[3][row];
    float Q = redQ[0][row] + redQ[1][row] + redQ[2][row] + redQ[3][row];
    float mean = S * (1.0f / 128.0f);
    float var = Q * (1.0f / 128.0f) - mean * mean;
    float rs = rsqrtf(var + 1e-5f);
    #pragma unroll
    for (int jt = 0; jt < 2; ++jt) {
      float y = (acc[jt][r] - mean) * rs * gv[jt] + bev[jt];
      y = fmaxf(y, 0.f);
      st[row * 136 + wid * 32 + jt * 16 + jcol] = f2bf(y);
    }
  }
  __syncthreads();
  int t = threadIdx.x;
  int row = t >> 4;
  int c = t & 15;
  uint4 v = *(const uint4*)&st[row * 136 + c * 8];
  *(uint4*)(outh + (size_t)(ntile * 16 + row) * DH + c * 8) = v;
}

// ---------------- final linear: out[:,128:384] = h@lin_w.T + lin_b ----------
__global__ __launch_bounds__(256) void final_kernel(const u16* __restrict__ A,
                                                    const u16* __restrict__ W,
                                                    const float* __restrict__ bias,
                                                    float* __restrict__ out) {
  __shared__ float smw[16 * 260];     // 1040B row stride: 16B aligned
  int lane = threadIdx.x & 63;
  int wid = threadIdx.x >> 6;
  int ntile = blockIdx.x;
  int rA = lane & 15;
  int ksel = lane >> 4;

  f32x4 acc[4];
  #pragma unroll
  for (int j = 0; j < 4; ++j) acc[j] = (f32x4){0.f,0.f,0.f,0.f};

  const u16* arow = A + (size_t)(ntile * 16 + rA) * DH + ksel * 8;
  #pragma unroll
  for (int ks = 0; ks < 4; ++ks) {
    bf16x8 af = *(const bf16x8*)(arow + ks * 32);
    #pragma unroll
    for (int jt2 = 0; jt2 < 4; ++jt2) {
      int jt = wid * 4 + jt2;
      const u16* wf = W + (size_t)(jt * 16 + rA) * DH + ksel * 8 + ks * 32;
      acc[jt2] = __builtin_amdgcn_mfma_f32_16x16x32_bf16(af, *(const bf16x8*)wf, acc[jt2], 0, 0, 0);
    }
  }

  int jcol = lane & 15;
  int rbase = (lane >> 4) * 4;
  int base = ntile * 16;

  #pragma unroll
  for (int jt2 = 0; jt2 < 4; ++jt2) {
    float bv = bias[(wid * 4 + jt2) * 16 + jcol];
    #pragma unroll
    for (int r = 0; r < 4; ++r)
      smw[(rbase + r) * 260 + wid * 64 + jt2 * 16 + jcol] = acc[jt2][r] + bv;
  }
  __syncthreads();
  #pragma unroll
  for (int i = 0; i < 4; ++i) {
    int row = i * 4 + wid;
    f32x4 v = *(const f32x4*)&smw[row * 260 + lane * 4];
    *(f32x4*)(out + (size_t)(base + row) * 384 + 128 + lane * 4) = v;
  }
}

extern "C" void kernel_launch(void* const* d_in, const int* in_sizes, int n_in,
                              void* d_out, int out_size, void* d_ws, size_t ws_size,
                              hipStream_t stream) {
  const float* x      = (const float*)d_in[0];
  const int*   ei     = (const int*)d_in[1];
  const float* pre_w  = (const float*)d_in[2];
  const float* pre_b  = (const float*)d_in[3];
  const float* pre_g  = (const float*)d_in[4];
  const float* pre_be = (const float*)d_in[5];
  const float* wl0    = (const float*)d_in[6];
  const float* wr0    = (const float*)d_in[7];
  const float* b0     = (const float*)d_in[8];
  const float* g0     = (const float*)d_in[9];
  const float* be0    = (const float*)d_in[10];
  const float* wl1    = (const float*)d_in[11];
  const float* wr1    = (const float*)d_in[12];
  const float* b1     = (const float*)d_in[13];
  const float* g1     = (const float*)d_in[14];
  const float* be1    = (const float*)d_in[15];
  const float* lin_w  = (const float*)d_in[16];
  const float* lin_b  = (const float*)d_in[17];
  float* out = (float*)d_out;

  char* ws = (char*)d_ws;
  size_t o = 0;
  auto alloc = [&](size_t bytes) { void* p = ws + o; o += (bytes + 255) & ~255ULL; return p; };
  u16* hA   = (u16*)alloc((size_t)NN * DH * 2);
  u16* hB   = (u16*)alloc((size_t)NN * DH * 2);
  u16* wb   = (u16*)alloc((size_t)114688 * 2);
  int* cnt     = (int*)alloc((size_t)NN * 4);
  int* off     = (int*)alloc((size_t)(NN + 1) * 4);
  int* fillpos = (int*)alloc((size_t)NN * 4);
  int* srcs    = (int*)alloc((size_t)NE * 4);
  int* partial = (int*)alloc((size_t)NBLK * 4);

  {
    long total4 = ((long)NN * DH + 114688 + NN) / 4;
    int blocks = (int)((total4 + 255) / 256);
    cast_all<<<blocks, 256, 0, stream>>>(x, pre_w, wl0, wr0, wl1, wr1, lin_w, out, wb, cnt);
  }
  count_kernel<<<NE / 256, 256, 0, stream>>>(ei, cnt);
  scan_part<<<NBLK, 256, 0, stream>>>(cnt, partial);
  scan_top<<<1, 256, 0, stream>>>(partial);
  scan_final<<<NBLK, 256, 0, stream>>>(cnt, partial, off, fillpos);
  fill_kernel<<<NE / 256, 256, 0, stream>>>(ei, fillpos, srcs);

  // pre-MP layer (fp32 x directly)
  pre_gemm<<<NTILES, 256, 0, stream>>>(x, wb + 0, pre_b, pre_g, pre_be, hA);
  // SAGE layer 0 (fused gather + dual GEMM + LN + ReLU)
  sage_fused<<<NTILES, 256, 0, stream>>>(hA, off, srcs, wb + 16384, wb + 32768,
                                         b0, g0, be0, hB);
  // SAGE layer 1
  sage_fused<<<NTILES, 256, 0, stream>>>(hB, off, srcs, wb + 49152, wb + 65536,
                                         b1, g1, be1, hA);
  // output linear (cols 128:384; x part already written by cast_all)
  final_kernel<<<NTILES, 256, 0, stream>>>(hA, wb + 81920, lin_b, out);
}

// Round 16
// 244.721 us; speedup vs baseline: 1.0435x; 1.0435x over previous
//
#include <hip/hip_runtime.h>
#include <hip/hip_bf16.h>

typedef unsigned short u16;
typedef unsigned int u32;
typedef __bf16 bf16x8 __attribute__((ext_vector_type(8)));
typedef float f32x4 __attribute__((ext_vector_type(4)));

#define NN 50000
#define NE 640000
#define DH 128
#define NTILES (NN / 16)        // 3125, exact
#define NBLK ((NN + 255) / 256) // 196 scan blocks

__device__ __forceinline__ u16 f2bf(float f) {
  u32 i = __float_as_uint(f);
  u32 r = (i + 0x7FFFu + ((i >> 16) & 1u)) >> 16;   // RNE
  return (u16)r;
}
__device__ __forceinline__ float bflo(u32 v) { return __uint_as_float(v << 16); }
__device__ __forceinline__ float bfhi(u32 v) { return __uint_as_float(v & 0xFFFF0000u); }

__device__ __forceinline__ bf16x8 pack8(f32x4 lo, f32x4 hi) {
  union { u16 u[8]; bf16x8 v; } r;
  r.u[0] = f2bf(lo[0]); r.u[1] = f2bf(lo[1]); r.u[2] = f2bf(lo[2]); r.u[3] = f2bf(lo[3]);
  r.u[4] = f2bf(hi[0]); r.u[5] = f2bf(hi[1]); r.u[6] = f2bf(hi[2]); r.u[7] = f2bf(hi[3]);
  return r.v;
}

// ------- cast weights fp32->bf16, copy x -> out[:,0:128], zero cnt -----------
// wb layout (elements): pre_w@0, wl0@16384, wr0@32768, wl1@49152, wr1@65536, lin_w@81920
__global__ void cast_all(const float* __restrict__ x,
                         const float* __restrict__ pw, const float* __restrict__ wl0,
                         const float* __restrict__ wr0, const float* __restrict__ wl1,
                         const float* __restrict__ wr1, const float* __restrict__ lw,
                         float* __restrict__ out, u16* __restrict__ wb,
                         int* __restrict__ cnt) {
  int idx = blockIdx.x * blockDim.x + threadIdx.x;
  long i4 = (long)idx * 4;
  const long XCNT = (long)NN * DH;      // 6,400,000
  const long WCNT = 114688;
  if (i4 < XCNT) {
    float4 v = *(const float4*)(x + i4);
    long row = i4 >> 7;
    long col = i4 & 127;
    *(float4*)(out + row * 384 + col) = v;
  } else if (i4 < XCNT + WCNT) {
    long w = i4 - XCNT;
    const float* src; long off;
    if (w < 16384)      { src = pw;  off = 0; }
    else if (w < 32768) { src = wl0; off = 16384; }
    else if (w < 49152) { src = wr0; off = 32768; }
    else if (w < 65536) { src = wl1; off = 49152; }
    else if (w < 81920) { src = wr1; off = 65536; }
    else                { src = lw;  off = 81920; }
    float4 v = *(const float4*)(src + (w - off));
    u32 a = (u32)f2bf(v.x) | ((u32)f2bf(v.y) << 16);
    u32 b = (u32)f2bf(v.z) | ((u32)f2bf(v.w) << 16);
    *(uint2*)(wb + w) = make_uint2(a, b);
  } else if (i4 < XCNT + WCNT + NN) {
    long c = i4 - XCNT - WCNT;           // NN divisible by 4
    *(int4*)(cnt + c) = make_int4(0, 0, 0, 0);
  }
}

// ---------------- CSR build ----------------
__global__ void count_kernel(const int* __restrict__ ei, int* __restrict__ cnt) {
  int e = blockIdx.x * blockDim.x + threadIdx.x;
  if (e < NE) atomicAdd(&cnt[ei[NE + e]], 1);
}

__global__ __launch_bounds__(256) void scan_part(const int* __restrict__ cnt,
                                                 int* __restrict__ partial) {
  __shared__ int sm[4];
  int i = blockIdx.x * 256 + threadIdx.x;
  int s = (i < NN) ? cnt[i] : 0;
  s += __shfl_xor(s, 1);  s += __shfl_xor(s, 2);  s += __shfl_xor(s, 4);
  s += __shfl_xor(s, 8);  s += __shfl_xor(s, 16); s += __shfl_xor(s, 32);
  if ((threadIdx.x & 63) == 0) sm[threadIdx.x >> 6] = s;
  __syncthreads();
  if (threadIdx.x == 0) partial[blockIdx.x] = sm[0] + sm[1] + sm[2] + sm[3];
}

__global__ __launch_bounds__(256) void scan_top(int* __restrict__ partial) {
  __shared__ int sm[256];
  int tid = threadIdx.x;
  int v = (tid < NBLK) ? partial[tid] : 0;
  sm[tid] = v;
  __syncthreads();
  for (int d = 1; d < 256; d <<= 1) {
    int t = (tid >= d) ? sm[tid - d] : 0;
    __syncthreads();
    sm[tid] += t;
    __syncthreads();
  }
  if (tid < NBLK) partial[tid] = sm[tid] - v;   // exclusive prefix
}

__global__ __launch_bounds__(256) void scan_final(const int* __restrict__ cnt,
                                                  const int* __restrict__ partial,
                                                  int* __restrict__ off,
                                                  int* __restrict__ fillpos) {
  __shared__ int sm[256];
  int tid = threadIdx.x;
  int i = blockIdx.x * 256 + tid;
  int v = (i < NN) ? cnt[i] : 0;
  sm[tid] = v;
  __syncthreads();
  for (int d = 1; d < 256; d <<= 1) {
    int t = (tid >= d) ? sm[tid - d] : 0;
    __syncthreads();
    sm[tid] += t;
    __syncthreads();
  }
  int excl = sm[tid] - v + partial[blockIdx.x];
  if (i < NN) { off[i] = excl; fillpos[i] = excl; }
  if (i == 0) off[NN] = NE;
}

__global__ void fill_kernel(const int* __restrict__ ei, int* __restrict__ fillpos,
                            int* __restrict__ srcs) {
  int e = blockIdx.x * blockDim.x + threadIdx.x;
  if (e < NE) {
    int d = ei[NE + e];
    int p = atomicAdd(&fillpos[d], 1);
    srcs[p] = ei[e];
  }
}

// ---------------- pre-MP: fp32-A GEMM + bias + LN + ReLU ------------------
__global__ __launch_bounds__(256) void pre_gemm(const float* __restrict__ X,
                                                const u16* __restrict__ W,
                                                const float* __restrict__ bias,
                                                const float* __restrict__ g,
                                                const float* __restrict__ be,
                                                u16* __restrict__ outh) {
  __shared__ u16 st[16 * 136];
  __shared__ float redS[4][16], redQ[4][16];
  int lane = threadIdx.x & 63;
  int wid = threadIdx.x >> 6;
  int ntile = blockIdx.x;
  int rA = lane & 15;
  int ksel = lane >> 4;

  f32x4 acc[2];
  acc[0] = (f32x4){0.f,0.f,0.f,0.f};
  acc[1] = (f32x4){0.f,0.f,0.f,0.f};

  const float* xrow = X + (size_t)(ntile * 16 + rA) * DH + ksel * 8;
  #pragma unroll
  for (int ks = 0; ks < 4; ++ks) {
    f32x4 lo = *(const f32x4*)(xrow + ks * 32);
    f32x4 hi = *(const f32x4*)(xrow + ks * 32 + 4);
    bf16x8 af = pack8(lo, hi);
    #pragma unroll
    for (int jt = 0; jt < 2; ++jt) {
      const u16* wf = W + (size_t)(wid * 32 + jt * 16 + rA) * DH + ksel * 8 + ks * 32;
      acc[jt] = __builtin_amdgcn_mfma_f32_16x16x32_bf16(af, *(const bf16x8*)wf, acc[jt], 0, 0, 0);
    }
  }

  int jcol = lane & 15;
  int rbase = (lane >> 4) * 4;
  float gv[2], bev[2];
  #pragma unroll
  for (int jt = 0; jt < 2; ++jt) {
    int j = wid * 32 + jt * 16 + jcol;
    float bi = bias[j];
    gv[jt] = g[j]; bev[jt] = be[j];
    #pragma unroll
    for (int r = 0; r < 4; ++r) acc[jt][r] += bi;
  }
  #pragma unroll
  for (int r = 0; r < 4; ++r) {
    float s = acc[0][r] + acc[1][r];
    float q = acc[0][r]*acc[0][r] + acc[1][r]*acc[1][r];
    s += __shfl_xor(s, 1); s += __shfl_xor(s, 2);
    s += __shfl_xor(s, 4); s += __shfl_xor(s, 8);
    q += __shfl_xor(q, 1); q += __shfl_xor(q, 2);
    q += __shfl_xor(q, 4); q += __shfl_xor(q, 8);
    if (jcol == 0) { redS[wid][rbase + r] = s; redQ[wid][rbase + r] = q; }
  }
  __syncthreads();
  #pragma unroll
  for (int r = 0; r < 4; ++r) {
    int row = rbase + r;
    float S = redS[0][row] + redS[1][row] + redS[2][row] + redS[3][row];
    float Q = redQ[0][row] + redQ[1][row] + redQ[2][row] + redQ[3][row];
    float mean = S * (1.0f / 128.0f);
    float var = Q * (1.0f / 128.0f) - mean * mean;
    float rs = rsqrtf(var + 1e-5f);
    #pragma unroll
    for (int jt = 0; jt < 2; ++jt) {
      float y = (acc[jt][r] - mean) * rs * gv[jt] + bev[jt];
      y = fmaxf(y, 0.f);
      st[row * 136 + wid * 32 + jt * 16 + jcol] = f2bf(y);
    }
  }
  __syncthreads();
  int t = threadIdx.x;
  int row = t >> 4;
  int c = t & 15;
  uint4 v = *(const uint4*)&st[row * 136 + c * 8];
  *(uint4*)(outh + (size_t)(ntile * 16 + row) * DH + c * 8) = v;
}

// ------- SAGE layer fused: gather-mean + dual GEMM + bias + LN + ReLU --------
// 16-lane sub per node; 8-deep batched edge loads. Column-quadrant dual MFMA.
// FUSE_FINAL=1: instead of writing h to global, apply the reshape linear
// (h @ lin_w^T + lin_b) in-kernel and write out[:,128:384] directly.
#define ACC8(v) { a0 += bflo(v.x); a1 += bfhi(v.x); a2 += bflo(v.y); a3 += bfhi(v.y); \
                  a4 += bflo(v.z); a5 += bfhi(v.z); a6 += bflo(v.w); a7 += bfhi(v.w); }
template<int FUSE_FINAL>
__global__ __launch_bounds__(256) void sage_fused(const u16* __restrict__ h,
                                                  const int* __restrict__ off,
                                                  const int* __restrict__ srcs,
                                                  const u16* __restrict__ WL,
                                                  const u16* __restrict__ WR,
                                                  const float* __restrict__ bias,
                                                  const float* __restrict__ g,
                                                  const float* __restrict__ be,
                                                  u16* __restrict__ outh,
                                                  const u16* __restrict__ LW,
                                                  const float* __restrict__ lb,
                                                  float* __restrict__ out) {
  __shared__ u16 aggt[16 * 136];
  __shared__ u16 st[16 * 136];
  __shared__ float redS[4][16], redQ[4][16];
  int lane = threadIdx.x & 63;
  int wid = threadIdx.x >> 6;
  int ntile = blockIdx.x;
  int sub = lane >> 4;        // 0..3: which node of the wave's quad
  int c16 = lane & 15;        // 16B chunk of the row
  int rA = c16;
  int ksel = sub;

  // preload root A fragments (this block's own 16 h-rows) before gathering
  const u16* arow = h + (size_t)(ntile * 16 + rA) * DH + ksel * 8;
  bf16x8 afr[4];
  #pragma unroll
  for (int ks = 0; ks < 4; ++ks) afr[ks] = *(const bf16x8*)(arow + ks * 32);

  // gather-mean: sub s of wave w owns node (w*4+s); 8-deep load batching
  {
    int lrow = wid * 4 + sub;
    int node = ntile * 16 + lrow;
    int e0 = off[node], e1 = off[node + 1];
    float a0=0,a1=0,a2=0,a3=0,a4=0,a5=0,a6=0,a7=0;
    const u16* hc = h + c16 * 8;
    int e = e0;
    for (; e + 7 < e1; e += 8) {
      int i0 = srcs[e],   i1 = srcs[e+1], i2 = srcs[e+2], i3 = srcs[e+3];
      int i4_ = srcs[e+4], i5 = srcs[e+5], i6 = srcs[e+6], i7 = srcs[e+7];
      uint4 v0 = *(const uint4*)(hc + (size_t)i0 * DH);
      uint4 v1 = *(const uint4*)(hc + (size_t)i1 * DH);
      uint4 v2 = *(const uint4*)(hc + (size_t)i2 * DH);
      uint4 v3 = *(const uint4*)(hc + (size_t)i3 * DH);
      uint4 v4 = *(const uint4*)(hc + (size_t)i4_ * DH);
      uint4 v5 = *(const uint4*)(hc + (size_t)i5 * DH);
      uint4 v6 = *(const uint4*)(hc + (size_t)i6 * DH);
      uint4 v7 = *(const uint4*)(hc + (size_t)i7 * DH);
      ACC8(v0); ACC8(v1); ACC8(v2); ACC8(v3);
      ACC8(v4); ACC8(v5); ACC8(v6); ACC8(v7);
    }
    if (e + 3 < e1) {
      int i0 = srcs[e], i1 = srcs[e+1], i2 = srcs[e+2], i3 = srcs[e+3];
      uint4 v0 = *(const uint4*)(hc + (size_t)i0 * DH);
      uint4 v1 = *(const uint4*)(hc + (size_t)i1 * DH);
      uint4 v2 = *(const uint4*)(hc + (size_t)i2 * DH);
      uint4 v3 = *(const uint4*)(hc + (size_t)i3 * DH);
      ACC8(v0); ACC8(v1); ACC8(v2); ACC8(v3);
      e += 4;
    }
    for (; e < e1; ++e) {
      int s = srcs[e];
      uint4 v = *(const uint4*)(hc + (size_t)s * DH);
      ACC8(v);
    }
    int deg = e1 - e0;
    float inv = 1.0f / (float)(deg > 0 ? deg : 1);
    uint4 o;
    o.x = (u32)f2bf(a0 * inv) | ((u32)f2bf(a1 * inv) << 16);
    o.y = (u32)f2bf(a2 * inv) | ((u32)f2bf(a3 * inv) << 16);
    o.z = (u32)f2bf(a4 * inv) | ((u32)f2bf(a5 * inv) << 16);
    o.w = (u32)f2bf(a6 * inv) | ((u32)f2bf(a7 * inv) << 16);
    *(uint4*)&aggt[lrow * 136 + c16 * 8] = o;
  }
  __syncthreads();

  // dual MFMA: agg@WL + root@WR, wave owns cols [wid*32, wid*32+32)
  f32x4 acc[2];
  acc[0] = (f32x4){0.f,0.f,0.f,0.f};
  acc[1] = (f32x4){0.f,0.f,0.f,0.f};
  #pragma unroll
  for (int ks = 0; ks < 4; ++ks) {
    bf16x8 afa = *(const bf16x8*)&aggt[rA * 136 + ksel * 8 + ks * 32];
    #pragma unroll
    for (int jt = 0; jt < 2; ++jt) {
      const u16* wf = WL + (size_t)(wid * 32 + jt * 16 + rA) * DH + ksel * 8 + ks * 32;
      acc[jt] = __builtin_amdgcn_mfma_f32_16x16x32_bf16(afa, *(const bf16x8*)wf, acc[jt], 0, 0, 0);
    }
  }
  #pragma unroll
  for (int ks = 0; ks < 4; ++ks) {
    #pragma unroll
    for (int jt = 0; jt < 2; ++jt) {
      const u16* wf = WR + (size_t)(wid * 32 + jt * 16 + rA) * DH + ksel * 8 + ks * 32;
      acc[jt] = __builtin_amdgcn_mfma_f32_16x16x32_bf16(afr[ks], *(const bf16x8*)wf, acc[jt], 0, 0, 0);
    }
  }

  // epilogue: D[row=(lane>>4)*4+r][col local=lane&15]; global col = wid*32+jt*16+jcol
  int jcol = lane & 15;
  int rbase = (lane >> 4) * 4;
  float gv[2], bev[2];
  #pragma unroll
  for (int jt = 0; jt < 2; ++jt) {
    int j = wid * 32 + jt * 16 + jcol;
    float bi = bias[j];
    gv[jt] = g[j]; bev[jt] = be[j];
    #pragma unroll
    for (int r = 0; r < 4; ++r) acc[jt][r] += bi;
  }
  #pragma unroll
  for (int r = 0; r < 4; ++r) {
    float s = acc[0][r] + acc[1][r];
    float q = acc[0][r]*acc[0][r] + acc[1][r]*acc[1][r];
    s += __shfl_xor(s, 1); s += __shfl_xor(s, 2);
    s += __shfl_xor(s, 4); s += __shfl_xor(s, 8);
    q += __shfl_xor(q, 1); q += __shfl_xor(q, 2);
    q += __shfl_xor(q, 4); q += __shfl_xor(q, 8);
    if (jcol == 0) { redS[wid][rbase + r] = s; redQ[wid][rbase + r] = q; }
  }
  __syncthreads();
  #pragma unroll
  for (int r = 0; r < 4; ++r) {
    int row = rbase + r;
    float S = redS[0][row] + redS[1][row] + redS[2][row] + redS[3][row];
    float Q = redQ[0][row] + redQ[1][row] + redQ[2][row] + redQ[3][row];
    float mean = S * (1.0f / 128.0f);
    float var = Q * (1.0f / 128.0f) - mean * mean;
    float rs = rsqrtf(var + 1e-5f);
    #pragma unroll
    for (int jt = 0; jt < 2; ++jt) {
      float y = (acc[jt][r] - mean) * rs * gv[jt] + bev[jt];
      y = fmaxf(y, 0.f);
      st[row * 136 + wid * 32 + jt * 16 + jcol] = f2bf(y);
    }
  }
  __syncthreads();

  if constexpr (!FUSE_FINAL) {
    // store h tile to global
    int t = threadIdx.x;
    int row = t >> 4;
    int c = t & 15;
    uint4 v = *(const uint4*)&st[row * 136 + c * 8];
    *(uint4*)(outh + (size_t)(ntile * 16 + row) * DH + c * 8) = v;
  } else {
    // reshape linear fused: out[:,128:384] = h @ LW^T + lb
    __shared__ float smw[16 * 260];
    // A fragments from st (same addressing as aggt read)
    bf16x8 afY[4];
    #pragma unroll
    for (int ks = 0; ks < 4; ++ks)
      afY[ks] = *(const bf16x8*)&st[rA * 136 + ksel * 8 + ks * 32];
    f32x4 acc2[4];
    #pragma unroll
    for (int j = 0; j < 4; ++j) acc2[j] = (f32x4){0.f,0.f,0.f,0.f};
    #pragma unroll
    for (int ks = 0; ks < 4; ++ks) {
      #pragma unroll
      for (int jt2 = 0; jt2 < 4; ++jt2) {
        const u16* wf = LW + (size_t)(wid * 64 + jt2 * 16 + rA) * DH + ksel * 8 + ks * 32;
        acc2[jt2] = __builtin_amdgcn_mfma_f32_16x16x32_bf16(afY[ks], *(const bf16x8*)wf, acc2[jt2], 0, 0, 0);
      }
    }
    int base = ntile * 16;
    #pragma unroll
    for (int jt2 = 0; jt2 < 4; ++jt2) {
      float bv = lb[(wid * 4 + jt2) * 16 + jcol];
      #pragma unroll
      for (int r = 0; r < 4; ++r)
        smw[(rbase + r) * 260 + wid * 64 + jt2 * 16 + jcol] = acc2[jt2][r] + bv;
    }
    __syncthreads();
    #pragma unroll
    for (int i = 0; i < 4; ++i) {
      int row = i * 4 + wid;
      f32x4 v = *(const f32x4*)&smw[row * 260 + lane * 4];
      *(f32x4*)(out + (size_t)(base + row) * 384 + 128 + lane * 4) = v;
    }
  }
}

extern "C" void kernel_launch(void* const* d_in, const int* in_sizes, int n_in,
                              void* d_out, int out_size, void* d_ws, size_t ws_size,
                              hipStream_t stream) {
  const float* x      = (const float*)d_in[0];
  const int*   ei     = (const int*)d_in[1];
  const float* pre_w  = (const float*)d_in[2];
  const float* pre_b  = (const float*)d_in[3];
  const float* pre_g  = (const float*)d_in[4];
  const float* pre_be = (const float*)d_in[5];
  const float* wl0    = (const float*)d_in[6];
  const float* wr0    = (const float*)d_in[7];
  const float* b0     = (const float*)d_in[8];
  const float* g0     = (const float*)d_in[9];
  const float* be0    = (const float*)d_in[10];
  const float* wl1    = (const float*)d_in[11];
  const float* wr1    = (const float*)d_in[12];
  const float* b1     = (const float*)d_in[13];
  const float* g1     = (const float*)d_in[14];
  const float* be1    = (const float*)d_in[15];
  const float* lin_w  = (const float*)d_in[16];
  const float* lin_b  = (const float*)d_in[17];
  float* out = (float*)d_out;

  char* ws = (char*)d_ws;
  size_t o = 0;
  auto alloc = [&](size_t bytes) { void* p = ws + o; o += (bytes + 255) & ~255ULL; return p; };
  u16* hA   = (u16*)alloc((size_t)NN * DH * 2);
  u16* hB   = (u16*)alloc((size_t)NN * DH * 2);
  u16* wb   = (u16*)alloc((size_t)114688 * 2);
  int* cnt     = (int*)alloc((size_t)NN * 4);
  int* off     = (int*)alloc((size_t)(NN + 1) * 4);
  int* fillpos = (int*)alloc((size_t)NN * 4);
  int* srcs    = (int*)alloc((size_t)NE * 4);
  int* partial = (int*)alloc((size_t)NBLK * 4);

  {
    long total4 = ((long)NN * DH + 114688 + NN) / 4;
    int blocks = (int)((total4 + 255) / 256);
    cast_all<<<blocks, 256, 0, stream>>>(x, pre_w, wl0, wr0, wl1, wr1, lin_w, out, wb, cnt);
  }
  count_kernel<<<NE / 256, 256, 0, stream>>>(ei, cnt);
  scan_part<<<NBLK, 256, 0, stream>>>(cnt, partial);
  scan_top<<<1, 256, 0, stream>>>(partial);
  scan_final<<<NBLK, 256, 0, stream>>>(cnt, partial, off, fillpos);
  fill_kernel<<<NE / 256, 256, 0, stream>>>(ei, fillpos, srcs);

  // pre-MP layer (fp32 x directly)
  pre_gemm<<<NTILES, 256, 0, stream>>>(x, wb + 0, pre_b, pre_g, pre_be, hA);
  // SAGE layer 0 (fused gather + dual GEMM + LN + ReLU)
  sage_fused<0><<<NTILES, 256, 0, stream>>>(hA, off, srcs, wb + 16384, wb + 32768,
                                            b0, g0, be0, hB, nullptr, nullptr, nullptr);
  // SAGE layer 1 + reshape linear fused (writes out[:,128:384] directly)
  sage_fused<1><<<NTILES, 256, 0, stream>>>(hB, off, srcs, wb + 49152, wb + 65536,
                                            b1, g1, be1, nullptr, wb + 81920, lin_b, out);
}